// Round 3
// baseline (63831.152 us; speedup 1.0000x reference)
//
#include <hip/hip_runtime.h>
#include <hip/hip_bf16.h>

#define Bn   1024
#define Tn   730
#define INn  64
#define Hn   512
#define Kn   576      // INn + Hn
#define G4n  2048     // 4*Hn

typedef __bf16 bf16x8 __attribute__((ext_vector_type(8)));
typedef float  f32x4  __attribute__((ext_vector_type(4)));

// ---------------- weight pre-pack: Wc[row][k] bf16, row = gate*512+j, k over [x|h] ----------
__global__ void convert_weights(const float* __restrict__ Wih,
                                const float* __restrict__ Whh,
                                __bf16* __restrict__ Wc) {
    int idx = blockIdx.x * 256 + threadIdx.x;
    if (idx >= G4n * Kn) return;
    int row = idx / Kn;
    int k   = idx - row * Kn;
    float v = (k < INn) ? Wih[row * INn + k] : Whh[row * Hn + (k - INn)];
    Wc[idx] = (__bf16)v;
}

__device__ __forceinline__ float sigf(float x)   { return 1.0f / (1.0f + __expf(-x)); }
__device__ __forceinline__ float tanhf_f(float x){ return 2.0f * sigf(2.0f * x) - 1.0f; }

// ---------------- persistent LSTM scan ----------------
// 256 blocks x 512 threads. Block = (mi: 64 batch rows) x (nj: 32 cols).
// Wave w (of 8): gate = w>>1, jsub = w&1 -> one gate x 16 cols; weights live in
// 72 VGPRs for the whole kernel. c state lives in 4 VGPRs per thread.
// Cross-block dep is only among the 16 blocks sharing mi -> group barrier.
// blk->(mi,nj): xcd = blk&7, slot = blk>>3; mi = xcd*2+(slot&1), nj = slot>>1
// => each mi-group is XCD-local under the blk%8 heuristic (perf only; fences
// are agent-scope so correctness is mapping-independent).
__global__ __launch_bounds__(512, 2) void lstm_persist(
    const float* __restrict__ xd,     // [B,T,IN]
    const float* __restrict__ bias,   // [4H]
    const __bf16* __restrict__ Wc,    // [4H][Kn]
    __bf16* __restrict__ h0,          // [B,H] buffer A (final h lands here)
    __bf16* __restrict__ h1,          // [B,H] buffer B
    unsigned int* __restrict__ bar)   // 16 groups x 32 uints (128B stride)
{
    // LDS: A-tile in MFMA-fragment order, 4 rg x 18 kb x 64 lanes x 16B = 73728B.
    // z-exchange (32KB) reuses the same region between syncthreads.
    __shared__ __align__(16) char smem[73728];
    bf16x8* aTile = (bf16x8*)smem;
    f32x4*  zBuf  = (f32x4*)smem;

    const int blk  = blockIdx.x;
    const int xcd  = blk & 7;
    const int slot = blk >> 3;
    const int mi   = xcd * 2 + (slot & 1);
    const int nj   = slot >> 1;
    const int m0   = mi << 6;
    const int j0   = nj << 5;

    const int tid  = threadIdx.x;
    const int wave = tid >> 6;
    const int lane = tid & 63;
    const int q    = lane >> 4;
    const int l16  = lane & 15;

    // ---- resident weights: wave's gate x 16 cols, all 18 k-blocks ----
    const int gate = wave >> 1;
    const int jsub = wave & 1;
    const int wrow = gate * Hn + j0 + jsub * 16 + l16;
    bf16x8 wreg[18];
    #pragma unroll
    for (int kb = 0; kb < 18; ++kb)
        wreg[kb] = *(const bf16x8*)(Wc + (size_t)wrow * Kn + kb * 32 + q * 8);

    // ---- pointwise ownership: thread -> (jsub ps, rowgroup prg, lane) ----
    const int ps    = tid >> 8;                    // 0..1
    const int prg   = (tid >> 6) & 3;              // 0..3
    const int plane = tid & 63;
    const int pcol  = j0 + ps * 16 + (plane & 15);
    const int prow0 = m0 + prg * 16 + ((plane >> 4) << 2);
    const float bi_ = bias[pcol];
    const float bf_ = bias[Hn + pcol];
    const float bg_ = bias[2 * Hn + pcol];
    const float bo_ = bias[3 * Hn + pcol];
    float creg[4] = {0.f, 0.f, 0.f, 0.f};

    unsigned int* cnt = bar + (mi << 5);           // one 128B line per group
    bool dead = false;

    for (int t = 0; t < Tn; ++t) {
        const __bf16* hread  = (t & 1) ? h1 : h0;
        __bf16*       hwrite = (t & 1) ? h0 : h1;

        // ---- phase 1: stage A-tile [x_t | h] into LDS, fragment order ----
        // cell c = (rg*18+kb)*64 + lane16B: A[m0+rg*16+l16][kb*32+q*8 .. +7]
        #pragma unroll
        for (int i = 0; i < 9; ++i) {
            const int c     = i * 512 + tid;
            const int laneC = c & 63;
            const int kc    = c >> 6;        // 0..71
            const int kb    = kc % 18;
            const int rg    = kc / 18;
            const int qc    = laneC >> 4;
            const int l16c  = laneC & 15;
            const int row   = m0 + rg * 16 + l16c;
            const int k0    = kb * 32 + qc * 8;
            bf16x8 v;
            if (kb < 2) {
                const float* xp = xd + (size_t)row * (Tn * INn) + (size_t)t * INn + k0;
                f32x4 xlo = *(const f32x4*)xp;
                f32x4 xhi = *(const f32x4*)(xp + 4);
                v[0] = (__bf16)xlo[0]; v[1] = (__bf16)xlo[1];
                v[2] = (__bf16)xlo[2]; v[3] = (__bf16)xlo[3];
                v[4] = (__bf16)xhi[0]; v[5] = (__bf16)xhi[1];
                v[6] = (__bf16)xhi[2]; v[7] = (__bf16)xhi[3];
            } else {
                v = *(const bf16x8*)(hread + (size_t)row * Hn + (k0 - 64));
            }
            aTile[c] = v;
        }
        __syncthreads();

        // ---- phase 2: MFMA, weights from registers, A from LDS ----
        f32x4 a0 = {0.f,0.f,0.f,0.f}, a1 = {0.f,0.f,0.f,0.f};
        f32x4 a2 = {0.f,0.f,0.f,0.f}, a3 = {0.f,0.f,0.f,0.f};
        #pragma unroll
        for (int kb = 0; kb < 18; ++kb) {
            const bf16x8 bfrag = wreg[kb];
            a0 = __builtin_amdgcn_mfma_f32_16x16x32_bf16(aTile[(0*18+kb)*64 + lane], bfrag, a0, 0, 0, 0);
            a1 = __builtin_amdgcn_mfma_f32_16x16x32_bf16(aTile[(1*18+kb)*64 + lane], bfrag, a1, 0, 0, 0);
            a2 = __builtin_amdgcn_mfma_f32_16x16x32_bf16(aTile[(2*18+kb)*64 + lane], bfrag, a2, 0, 0, 0);
            a3 = __builtin_amdgcn_mfma_f32_16x16x32_bf16(aTile[(3*18+kb)*64 + lane], bfrag, a3, 0, 0, 0);
        }
        __syncthreads();   // A-tile reads done; safe to overwrite with z

        // ---- phase 3: z exchange via LDS (wave-linear, conflict-free) ----
        zBuf[(wave * 4 + 0) * 64 + lane] = a0;
        zBuf[(wave * 4 + 1) * 64 + lane] = a1;
        zBuf[(wave * 4 + 2) * 64 + lane] = a2;
        zBuf[(wave * 4 + 3) * 64 + lane] = a3;
        __syncthreads();

        // ---- phase 4: gate pointwise; c in registers; h -> global ----
        const f32x4 zi = zBuf[((0 * 2 + ps) * 4 + prg) * 64 + plane];
        const f32x4 zf = zBuf[((1 * 2 + ps) * 4 + prg) * 64 + plane];
        const f32x4 zg = zBuf[((2 * 2 + ps) * 4 + prg) * 64 + plane];
        const f32x4 zo = zBuf[((3 * 2 + ps) * 4 + prg) * 64 + plane];
        #pragma unroll
        for (int r = 0; r < 4; ++r) {
            const float cn = sigf(zf[r] + bf_) * creg[r] + sigf(zi[r] + bi_) * tanhf_f(zg[r] + bg_);
            creg[r] = cn;
            hwrite[(size_t)(prow0 + r) * Hn + pcol] = (__bf16)(sigf(zo[r] + bo_) * tanhf_f(cn));
        }

        // ---- phase 5: group barrier (16 blocks sharing mi) ----
        __threadfence();           // release h stores to device scope
        __syncthreads();
        if (tid == 0) {
            __hip_atomic_fetch_add(cnt, 1u, __ATOMIC_ACQ_REL, __HIP_MEMORY_SCOPE_AGENT);
            if (!dead) {
                const unsigned int target = 16u * (unsigned int)(t + 1);
                int spins = 0;
                while (__hip_atomic_load(cnt, __ATOMIC_ACQUIRE, __HIP_MEMORY_SCOPE_AGENT) < target) {
                    __builtin_amdgcn_s_sleep(2);
                    if (++spins > 2000000) { dead = true; break; }  // hang -> fast wrong-answer
                }
            }
        }
        __syncthreads();
        __threadfence();           // acquire: invalidate caches before next h read
    }
}

// ---------------- head: out[b] = relu(dot(h_T[b], Wl) + bl) ----------------
__global__ void head_kernel(const __bf16* __restrict__ h, const float* __restrict__ Wl,
                            const float* __restrict__ bl, float* __restrict__ out) {
    const int b = blockIdx.x;
    const int lane = threadIdx.x;  // 64 threads
    const __bf16* hp = h + (size_t)b * Hn;
    float s = 0.f;
    #pragma unroll
    for (int j = lane; j < Hn; j += 64) s += (float)hp[j] * Wl[j];
    #pragma unroll
    for (int off = 32; off > 0; off >>= 1) s += __shfl_down(s, off, 64);
    if (lane == 0) out[b] = fmaxf(s + bl[0], 0.0f);
}

extern "C" void kernel_launch(void* const* d_in, const int* in_sizes, int n_in,
                              void* d_out, int out_size, void* d_ws, size_t ws_size,
                              hipStream_t stream) {
    const float* xd  = (const float*)d_in[0];
    const float* Wih = (const float*)d_in[1];
    const float* Whh = (const float*)d_in[2];
    const float* b   = (const float*)d_in[3];
    const float* Wl  = (const float*)d_in[4];
    const float* bl  = (const float*)d_in[5];
    float* out = (float*)d_out;

    // ws layout:
    //   Wc  bf16 [2048][576] : 2,359,296 B
    //   h0  bf16 [1024][512] : 1,048,576 B
    //   h1  bf16 [1024][512] : 1,048,576 B
    //   bar u32  [16][32]    : 2,048 B      (~4.46 MB total)
    char* ws = (char*)d_ws;
    __bf16* Wc = (__bf16*)ws;
    __bf16* h0 = (__bf16*)(ws + 2359296);
    __bf16* h1 = (__bf16*)(ws + 2359296 + 1048576);
    unsigned int* bar = (unsigned int*)(ws + 2359296 + 2 * 1048576);

    hipMemsetAsync(h0, 0, 1048576, stream);   // t=0 reads h0 as zeros
    hipMemsetAsync(bar, 0, 2048, stream);     // monotonic barrier counters

    const int total = G4n * Kn;
    convert_weights<<<(total + 255) / 256, 256, 0, stream>>>(Wih, Whh, Wc);

    lstm_persist<<<256, 512, 0, stream>>>(xd, b, Wc, h0, h1, bar);

    // t=729 (odd) writes h0 -> final hidden state is in h0
    head_kernel<<<Bn, 64, 0, stream>>>(h0, Wl, bl, out);
}

// Round 4
// 6049.241 us; speedup vs baseline: 10.5519x; 10.5519x over previous
//
#include <hip/hip_runtime.h>
#include <hip/hip_bf16.h>

#define Bn   1024
#define Tn   730
#define INn  64
#define Hn   512
#define Kn   576      // INn + Hn
#define G4n  2048     // 4*Hn

typedef __bf16 bf16x8 __attribute__((ext_vector_type(8)));
typedef float  f32x4  __attribute__((ext_vector_type(4)));

// ---------------- weight pre-pack: Wc[row][k] bf16, row = gate*512+j, k over [x|h] ----------
__global__ void convert_weights(const float* __restrict__ Wih,
                                const float* __restrict__ Whh,
                                __bf16* __restrict__ Wc) {
    int idx = blockIdx.x * 256 + threadIdx.x;
    if (idx >= G4n * Kn) return;
    int row = idx / Kn;
    int k   = idx - row * Kn;
    float v = (k < INn) ? Wih[row * INn + k] : Whh[row * Hn + (k - INn)];
    Wc[idx] = (__bf16)v;
}

__device__ __forceinline__ float sigf(float x)   { return 1.0f / (1.0f + __expf(-x)); }
__device__ __forceinline__ float tanhf_f(float x){ return 2.0f * sigf(2.0f * x) - 1.0f; }

// ---------------- persistent LSTM scan ----------------
// 256 blocks x 512 threads. Block = (mi: 64 batch rows) x (nj: 32 cols).
// Wave w (of 8): gate = w>>1, jsub = w&1 -> one gate x 16 cols; weights in 72 VGPRs.
// c state in 4 VGPRs/thread. Cross-block dep only among 16 blocks sharing mi.
// COHERENCE: all cross-block data (h, counters) moves via RELAXED agent-scope
// atomics -> sc1 write-through/bypass of L2 (per-line, no buffer_wbl2/inv).
// Ordering: __syncthreads() emits s_waitcnt vmcnt(0) before s_barrier, draining
// the write-through h stores to IC before the barrier counter is bumped.
__global__ __launch_bounds__(512, 2) void lstm_persist(
    const float* __restrict__ xd,     // [B,T,IN]
    const float* __restrict__ bias,   // [4H]
    const __bf16* __restrict__ Wc,    // [4H][Kn]
    __bf16* __restrict__ h0,          // [B,H] buffer A (final h lands here)
    __bf16* __restrict__ h1,          // [B,H] buffer B
    unsigned int* __restrict__ bar)   // 16 groups x 32 uints (128B stride)
{
    // LDS: A-tile in MFMA-fragment order, 4 rg x 18 kb x 64 lanes x 16B = 73728B.
    // z-exchange (32KB) reuses the same region between syncthreads.
    __shared__ __align__(16) char smem[73728];
    bf16x8* aTile = (bf16x8*)smem;
    f32x4*  zBuf  = (f32x4*)smem;
    float*  zf32  = (float*)smem;

    const int blk  = blockIdx.x;
    const int xcd  = blk & 7;
    const int slot = blk >> 3;
    const int mi   = xcd * 2 + (slot & 1);
    const int nj   = slot >> 1;
    const int m0   = mi << 6;
    const int j0   = nj << 5;

    const int tid  = threadIdx.x;
    const int wave = tid >> 6;
    const int lane = tid & 63;
    const int q    = lane >> 4;
    const int l16  = lane & 15;

    // ---- resident weights: wave's gate x 16 cols, all 18 k-blocks ----
    const int gate = wave >> 1;
    const int jsub = wave & 1;
    const int wrow = gate * Hn + j0 + jsub * 16 + l16;
    bf16x8 wreg[18];
    #pragma unroll
    for (int kb = 0; kb < 18; ++kb)
        wreg[kb] = *(const bf16x8*)(Wc + (size_t)wrow * Kn + kb * 32 + q * 8);

    // ---- pointwise ownership: thread -> (1 row, 4 consecutive cols) ----
    const int pr   = tid >> 3;             // 0..63 row within m-tile
    const int pc4  = (tid & 7) << 2;       // col group start within 32
    const int prow = m0 + pr;
    const int jsub_p   = pc4 >> 4;
    const int rg_p     = pr >> 4;
    const int r_p      = pr & 3;
    const int lanebase = (((pr >> 2) & 3) << 4) | (pc4 & 15);
    const f32x4 bi4 = *(const f32x4*)(bias + j0 + pc4);
    const f32x4 bf4 = *(const f32x4*)(bias + Hn + j0 + pc4);
    const f32x4 bg4 = *(const f32x4*)(bias + 2 * Hn + j0 + pc4);
    const f32x4 bo4 = *(const f32x4*)(bias + 3 * Hn + j0 + pc4);
    float creg[4] = {0.f, 0.f, 0.f, 0.f};

    unsigned int* cnt = bar + (mi << 5);   // one 128B line per group
    bool dead = false;

    for (int t = 0; t < Tn; ++t) {
        const __bf16* hread  = (t & 1) ? h1 : h0;
        __bf16*       hwrite = (t & 1) ? h0 : h1;

        // ---- phase 1: stage A-tile [x_t | h] into LDS, fragment order ----
        #pragma unroll
        for (int i = 0; i < 9; ++i) {
            const int c     = i * 512 + tid;
            const int laneC = c & 63;
            const int kc    = c >> 6;        // 0..71
            const int kb    = kc % 18;
            const int rg    = kc / 18;
            const int qc    = laneC >> 4;
            const int l16c  = laneC & 15;
            const int row   = m0 + rg * 16 + l16c;
            const int k0    = kb * 32 + qc * 8;
            bf16x8 v;
            if (kb < 2) {
                const float* xp = xd + (size_t)row * (Tn * INn) + (size_t)t * INn + k0;
                f32x4 xlo = *(const f32x4*)xp;
                f32x4 xhi = *(const f32x4*)(xp + 4);
                v[0] = (__bf16)xlo[0]; v[1] = (__bf16)xlo[1];
                v[2] = (__bf16)xlo[2]; v[3] = (__bf16)xlo[3];
                v[4] = (__bf16)xhi[0]; v[5] = (__bf16)xhi[1];
                v[6] = (__bf16)xhi[2]; v[7] = (__bf16)xhi[3];
            } else {
                const unsigned long long* hp =
                    (const unsigned long long*)(hread + (size_t)row * Hn + (k0 - 64));
                union { unsigned long long u[2]; bf16x8 v8; } cv;
                cv.u[0] = __hip_atomic_load(hp,     __ATOMIC_RELAXED, __HIP_MEMORY_SCOPE_AGENT);
                cv.u[1] = __hip_atomic_load(hp + 1, __ATOMIC_RELAXED, __HIP_MEMORY_SCOPE_AGENT);
                v = cv.v8;
            }
            aTile[c] = v;
        }
        __syncthreads();

        // ---- phase 2: MFMA, weights from registers, A from LDS ----
        f32x4 a0 = {0.f,0.f,0.f,0.f}, a1 = {0.f,0.f,0.f,0.f};
        f32x4 a2 = {0.f,0.f,0.f,0.f}, a3 = {0.f,0.f,0.f,0.f};
        #pragma unroll
        for (int kb = 0; kb < 18; ++kb) {
            const bf16x8 bfrag = wreg[kb];
            a0 = __builtin_amdgcn_mfma_f32_16x16x32_bf16(aTile[(0*18+kb)*64 + lane], bfrag, a0, 0, 0, 0);
            a1 = __builtin_amdgcn_mfma_f32_16x16x32_bf16(aTile[(1*18+kb)*64 + lane], bfrag, a1, 0, 0, 0);
            a2 = __builtin_amdgcn_mfma_f32_16x16x32_bf16(aTile[(2*18+kb)*64 + lane], bfrag, a2, 0, 0, 0);
            a3 = __builtin_amdgcn_mfma_f32_16x16x32_bf16(aTile[(3*18+kb)*64 + lane], bfrag, a3, 0, 0, 0);
        }
        __syncthreads();   // A-tile reads done; safe to overwrite with z

        // ---- phase 3: z exchange via LDS ----
        zBuf[(wave * 4 + 0) * 64 + lane] = a0;
        zBuf[(wave * 4 + 1) * 64 + lane] = a1;
        zBuf[(wave * 4 + 2) * 64 + lane] = a2;
        zBuf[(wave * 4 + 3) * 64 + lane] = a3;
        __syncthreads();

        // ---- phase 4: gate pointwise; c in regs; h -> global via u64 write-through ----
        float zv[4][4];
        #pragma unroll
        for (int g = 0; g < 4; ++g) {
            const int cellbase = (((g << 1) + jsub_p) * 4 + rg_p) * 64 + lanebase;
            #pragma unroll
            for (int cc = 0; cc < 4; ++cc)
                zv[g][cc] = zf32[((cellbase + cc) << 2) + r_p];
        }
        union { unsigned long long u; __bf16 h[4]; } pk;
        #pragma unroll
        for (int cc = 0; cc < 4; ++cc) {
            const float cn = sigf(zv[1][cc] + bf4[cc]) * creg[cc]
                           + sigf(zv[0][cc] + bi4[cc]) * tanhf_f(zv[2][cc] + bg4[cc]);
            creg[cc] = cn;
            pk.h[cc] = (__bf16)(sigf(zv[3][cc] + bo4[cc]) * tanhf_f(cn));
        }
        __hip_atomic_store((unsigned long long*)(hwrite + (size_t)prow * Hn + j0 + pc4),
                           pk.u, __ATOMIC_RELAXED, __HIP_MEMORY_SCOPE_AGENT);

        // ---- phase 5: group barrier (16 blocks sharing mi), relaxed atomics only ----
        __syncthreads();   // drains vmcnt(0): all write-through h stores at IC
        if (tid == 0) {
            __hip_atomic_fetch_add(cnt, 1u, __ATOMIC_RELAXED, __HIP_MEMORY_SCOPE_AGENT);
            if (!dead) {
                const unsigned int target = 16u * (unsigned int)(t + 1);
                int spins = 0;
                while (__hip_atomic_load(cnt, __ATOMIC_RELAXED, __HIP_MEMORY_SCOPE_AGENT) < target) {
                    __builtin_amdgcn_s_sleep(2);
                    if (++spins > 300000) { dead = true; break; }  // hang -> fast wrong-answer
                }
            }
        }
        __syncthreads();
    }
}

// ---------------- head: out[b] = relu(dot(h_T[b], Wl) + bl) ----------------
__global__ void head_kernel(const __bf16* __restrict__ h, const float* __restrict__ Wl,
                            const float* __restrict__ bl, float* __restrict__ out) {
    const int b = blockIdx.x;
    const int lane = threadIdx.x;  // 64 threads
    const __bf16* hp = h + (size_t)b * Hn;
    float s = 0.f;
    #pragma unroll
    for (int j = lane; j < Hn; j += 64) s += (float)hp[j] * Wl[j];
    #pragma unroll
    for (int off = 32; off > 0; off >>= 1) s += __shfl_down(s, off, 64);
    if (lane == 0) out[b] = fmaxf(s + bl[0], 0.0f);
}

extern "C" void kernel_launch(void* const* d_in, const int* in_sizes, int n_in,
                              void* d_out, int out_size, void* d_ws, size_t ws_size,
                              hipStream_t stream) {
    const float* xd  = (const float*)d_in[0];
    const float* Wih = (const float*)d_in[1];
    const float* Whh = (const float*)d_in[2];
    const float* b   = (const float*)d_in[3];
    const float* Wl  = (const float*)d_in[4];
    const float* bl  = (const float*)d_in[5];
    float* out = (float*)d_out;

    // ws layout:
    //   Wc  bf16 [2048][576] : 2,359,296 B
    //   h0  bf16 [1024][512] : 1,048,576 B
    //   h1  bf16 [1024][512] : 1,048,576 B
    //   bar u32  [16][32]    : 2,048 B
    char* ws = (char*)d_ws;
    __bf16* Wc = (__bf16*)ws;
    __bf16* h0 = (__bf16*)(ws + 2359296);
    __bf16* h1 = (__bf16*)(ws + 2359296 + 1048576);
    unsigned int* bar = (unsigned int*)(ws + 2359296 + 2 * 1048576);

    hipMemsetAsync(h0, 0, 1048576, stream);   // t=0 reads h0 as zeros
    hipMemsetAsync(bar, 0, 2048, stream);     // monotonic barrier counters

    const int total = G4n * Kn;
    convert_weights<<<(total + 255) / 256, 256, 0, stream>>>(Wih, Whh, Wc);

    lstm_persist<<<256, 512, 0, stream>>>(xd, b, Wc, h0, h1, bar);

    // t=729 (odd) writes h0 -> final hidden state is in h0
    head_kernel<<<Bn, 64, 0, stream>>>(h0, Wl, bl, out);
}